// Round 3
// baseline (5374.889 us; speedup 1.0000x reference)
//
#include <hip/hip_runtime.h>
#include <hip/hip_bf16.h>

typedef __bf16 bf16_t;
typedef bf16_t bf16x8 __attribute__((ext_vector_type(8)));
typedef bf16_t bf16x4 __attribute__((ext_vector_type(4)));
typedef bf16_t bf16x2 __attribute__((ext_vector_type(2)));
typedef float f32x4 __attribute__((ext_vector_type(4)));

// ---------------------------------------------------------------------------
// async global -> LDS, 16B per lane (wave-uniform LDS base, HW adds lane*16)
// ---------------------------------------------------------------------------
__device__ __forceinline__ void load_lds16(const bf16_t* g, bf16_t* l) {
  __builtin_amdgcn_global_load_lds(
      (const __attribute__((address_space(1))) unsigned int*)g,
      (__attribute__((address_space(3))) unsigned int*)l,
      16, 0, 0);
}

// ---------------------------------------------------------------------------
__global__ void conv_f32_bf16(const float* __restrict__ src,
                              bf16_t* __restrict__ dst, long n) {
  long i = ((long)blockIdx.x * blockDim.x + threadIdx.x) * 8;
  if (i + 7 >= n) return;
  float4 a = *(const float4*)(src + i);
  float4 b = *(const float4*)(src + i + 4);
  bf16x8 v;
  v[0] = (bf16_t)a.x; v[1] = (bf16_t)a.y; v[2] = (bf16_t)a.z; v[3] = (bf16_t)a.w;
  v[4] = (bf16_t)b.x; v[5] = (bf16_t)b.y; v[6] = (bf16_t)b.z; v[7] = (bf16_t)b.w;
  *(bf16x8*)(dst + i) = v;
}

__global__ void conv_bf16_f32(const bf16_t* __restrict__ src,
                              float* __restrict__ dst, long n) {
  long i = (long)blockIdx.x * blockDim.x + threadIdx.x;
  if (i >= n) return;
  dst[i] = (float)src[i];
}

__global__ void transpose_conv(const float* __restrict__ src,
                               bf16_t* __restrict__ dst, int Ksrc, int Nsrc) {
  __shared__ float tile[32][33];
  int n0 = blockIdx.x * 32, k0 = blockIdx.y * 32;
  int tx = threadIdx.x, ty = threadIdx.y;  // (32, 8)
#pragma unroll
  for (int i = 0; i < 32; i += 8)
    tile[ty + i][tx] = src[(long)(k0 + ty + i) * Nsrc + n0 + tx];
  __syncthreads();
#pragma unroll
  for (int i = 0; i < 32; i += 8)
    dst[(long)(n0 + ty + i) * Ksrc + k0 + tx] = (bf16_t)tile[tx][ty + i];
}

// ---------------------------------------------------------------------------
// m97-style GEMM: D[M,N] = A[M,K] @ Bt[N,K]^T + bias
// ---------------------------------------------------------------------------
template <int STORE_MODE>
__global__ __launch_bounds__(256) void gemm_bt_128(
    const bf16_t* __restrict__ A, const bf16_t* __restrict__ Bt,
    const float* __restrict__ bias, void* __restrict__ Dout,
    int M, int N, int K) {
  __shared__ bf16_t As[128 * 32];
  __shared__ bf16_t Bs[128 * 32];
  const int tid = threadIdx.x;
  const int lane = tid & 63;
  const int w = tid >> 6;
  const int wr = w >> 1, wc = w & 1;
  const int m0 = blockIdx.y * 128, n0 = blockIdx.x * 128;

  f32x4 acc[4][4] = {};

  const int r0 = tid >> 2;
  const int kk = (tid & 3) * 8;
  const int fr = lane & 15;
  const int fk = (lane >> 4) * 8;

  for (int k0 = 0; k0 < K; k0 += 32) {
    load_lds16(A + (long)(m0 + r0) * K + k0 + kk, As + w * 512);
    load_lds16(A + (long)(m0 + 64 + r0) * K + k0 + kk, As + 2048 + w * 512);
    load_lds16(Bt + (long)(n0 + r0) * K + k0 + kk, Bs + w * 512);
    load_lds16(Bt + (long)(n0 + 64 + r0) * K + k0 + kk, Bs + 2048 + w * 512);
    asm volatile("s_waitcnt vmcnt(0)" ::: "memory");
    __syncthreads();

    bf16x8 af[4], bfx[4];
#pragma unroll
    for (int m = 0; m < 4; ++m)
      af[m] = *(const bf16x8*)&As[(wr * 64 + m * 16 + fr) * 32 + fk];
#pragma unroll
    for (int n = 0; n < 4; ++n)
      bfx[n] = *(const bf16x8*)&Bs[(wc * 64 + n * 16 + fr) * 32 + fk];
#pragma unroll
    for (int m = 0; m < 4; ++m)
#pragma unroll
      for (int n = 0; n < 4; ++n)
        acc[m][n] = __builtin_amdgcn_mfma_f32_16x16x32_bf16(af[m], bfx[n],
                                                            acc[m][n], 0, 0, 0);
    __syncthreads();
  }

  const int fq = lane >> 4;
#pragma unroll
  for (int m = 0; m < 4; ++m) {
#pragma unroll
    for (int n = 0; n < 4; ++n) {
      int col = n0 + wc * 64 + n * 16 + fr;
      float bv = bias[col];
#pragma unroll
      for (int r = 0; r < 4; ++r) {
        int row = m0 + wr * 64 + m * 16 + fq * 4 + r;
        float v = acc[m][n][r] + bv;
        if (STORE_MODE == 0)
          ((float*)Dout)[(long)row * N + col] = v;
        else
          ((bf16_t*)Dout)[(long)row * N + col] = (bf16_t)v;
      }
    }
  }
}

// ---------------------------------------------------------------------------
// Persistent recurrence kernel: 256 WGs (1/CU), 256 thr (4 waves).
// WG (r,j): rows r*32..+32, cols j*32..+32 of h, for ALL 256 steps.
// Wave w holds its W_hh B-operand slice (32 cols x 512 K) in 128 VGPRs,
// loaded once. Per step: direct-global A-frags of h_prev + 64 MFMA,
// LDS cross-wave K-reduce, fused Z-add+ReLU+bf16 store in place.
// Sync: h_t row-slab r consumed only by row-group r (64 WGs) -> 4 independent
// monotonic counters, release-add / relaxed-spin + acquire (agent scope).
// gid swizzle: group r on XCD pair {2r, 2r+1} for h L2 locality.
// ---------------------------------------------------------------------------
__global__ __launch_bounds__(256, 1) void rnn_persistent(
    const bf16_t* __restrict__ h0,
    bf16_t* __restrict__ Hbuf,        // Z in, h out, (T,B,H) bf16
    const bf16_t* __restrict__ WhhT,  // (H_out_col, K) = (2048, 2048) bf16
    unsigned int* __restrict__ ctr) { // 4 counters, 256B apart, pre-zeroed
  __shared__ float sred[4][1024];  // 16 KB

  const int tid = threadIdx.x, lane = tid & 63, w = tid >> 6;
  const int gid = blockIdx.x;
  const int r = (gid & 7) >> 1;                    // row group 0..3
  const int j = ((gid >> 3) << 1) | (gid & 1);     // col member 0..63
  const int m0 = r * 32, n0 = j * 32;
  const int H = 2048;
  const long BH = 128L * 2048;
  const int kb = w * 512;
  const int fr = lane & 15, fg = lane >> 4;

  // ---- preload W_hh slice into registers (once) ----
  bf16x8 bfrag[2][16];
#pragma unroll
  for (int cf = 0; cf < 2; ++cf)
#pragma unroll
    for (int ks = 0; ks < 16; ++ks)
      bfrag[cf][ks] = *(const bf16x8*)(WhhT + (long)(n0 + cf * 16 + fr) * H +
                                       kb + ks * 32 + fg * 8);

  // epilogue element ownership: 4 contiguous cols per thread
  const int jj = tid * 4;
  const int zrow = jj >> 5, zcol = jj & 31;
  const long zoff = (long)(m0 + zrow) * H + n0 + zcol;

  unsigned int* myctr = ctr + r * 64;  // 256B-spaced counters

  for (int t = 0; t < 256; ++t) {
    const bf16_t* hp = (t == 0) ? h0 : Hbuf + (long)(t - 1) * BH;
    bf16_t* z = Hbuf + (long)t * BH;

    if (t > 0) {
      if (tid == 0) {
        const unsigned int target = (unsigned int)(64 * t);
        while (__hip_atomic_load(myctr, __ATOMIC_RELAXED,
                                 __HIP_MEMORY_SCOPE_AGENT) < target)
          __builtin_amdgcn_s_sleep(2);
      }
      __syncthreads();
      __builtin_amdgcn_fence(__ATOMIC_ACQUIRE, "agent");
    }

    // prefetch Z for the epilogue (independent of h_prev)
    bf16x4 zv = *(const bf16x4*)(z + zoff);

    // ---- MFMA phase: A-frags direct from global (L2) ----
    const bf16_t* Ab = hp + (long)(m0 + fr) * H + kb + fg * 8;
    f32x4 acc[2][2] = {};
#pragma unroll
    for (int ks = 0; ks < 16; ++ks) {
      bf16x8 a0 = *(const bf16x8*)(Ab + ks * 32);
      bf16x8 a1 = *(const bf16x8*)(Ab + (long)16 * H + ks * 32);
      acc[0][0] = __builtin_amdgcn_mfma_f32_16x16x32_bf16(a0, bfrag[0][ks], acc[0][0], 0, 0, 0);
      acc[0][1] = __builtin_amdgcn_mfma_f32_16x16x32_bf16(a0, bfrag[1][ks], acc[0][1], 0, 0, 0);
      acc[1][0] = __builtin_amdgcn_mfma_f32_16x16x32_bf16(a1, bfrag[0][ks], acc[1][0], 0, 0, 0);
      acc[1][1] = __builtin_amdgcn_mfma_f32_16x16x32_bf16(a1, bfrag[1][ks], acc[1][1], 0, 0, 0);
    }

    // ---- cross-wave K-reduction ----
#pragma unroll
    for (int mf = 0; mf < 2; ++mf)
#pragma unroll
      for (int cf = 0; cf < 2; ++cf)
#pragma unroll
        for (int rr = 0; rr < 4; ++rr)
          sred[w][(mf * 16 + fg * 4 + rr) * 32 + cf * 16 + fr] = acc[mf][cf][rr];
    __syncthreads();

    bf16x4 o;
#pragma unroll
    for (int c4 = 0; c4 < 4; ++c4) {
      float s = sred[0][jj + c4] + sred[1][jj + c4] + sred[2][jj + c4] +
                sred[3][jj + c4];
      float v = s + (float)zv[c4];
      o[c4] = (bf16_t)(v > 0.f ? v : 0.f);
    }
    *(bf16x4*)(z + zoff) = o;

    // all threads' stores complete before the group signal; also protects
    // sred WAR for the next iteration.
    __syncthreads();
    if (tid == 0)
      __hip_atomic_fetch_add(myctr, 1u, __ATOMIC_RELEASE,
                             __HIP_MEMORY_SCOPE_AGENT);
  }
}

// ---------------------------------------------------------------------------
extern "C" void kernel_launch(void* const* d_in, const int* in_sizes, int n_in,
                              void* d_out, int out_size, void* d_ws,
                              size_t ws_size, hipStream_t stream) {
  const float* x   = (const float*)d_in[0];  // (T,B,D)
  const float* h0  = (const float*)d_in[1];  // (B,H)
  const float* Wxh = (const float*)d_in[2];  // (D,H)
  const float* Whh = (const float*)d_in[3];  // (H,H)
  const float* bh  = (const float*)d_in[4];  // (H,)
  const float* Whq = (const float*)d_in[5];  // (H,Q)
  const float* bq  = (const float*)d_in[6];  // (Q,)
  float* out = (float*)d_out;

  const int T = 256, B = 128, D = 1024, H = 2048, Q = 1024;
  const long MB = (long)T * B;  // 32768

  char* ws = (char*)d_ws;
  unsigned int* ctr = (unsigned int*)ws;  ws += 1024;     // 4 x 256B counters
  bf16_t* x_bf = (bf16_t*)ws;  ws += MB * D * 2;          // 64 MiB
  bf16_t* Hbuf = (bf16_t*)ws;  ws += MB * H * 2;          // 128 MiB (Z -> h)
  bf16_t* h0bf = (bf16_t*)ws;  ws += (long)B * H * 2;
  bf16_t* WxhT = (bf16_t*)ws;  ws += (long)H * D * 2;
  bf16_t* WhhT = (bf16_t*)ws;  ws += (long)H * H * 2;
  bf16_t* WhqT = (bf16_t*)ws;  ws += (long)Q * H * 2;

  // zero the barrier counters (fresh every launch -> deterministic)
  hipMemsetAsync(ctr, 0, 1024, stream);

  // --- convert inputs to bf16 (weights transposed to N x K) ---
  conv_f32_bf16<<<(int)(MB * D / 8 / 256), 256, 0, stream>>>(x, x_bf, MB * D);
  conv_f32_bf16<<<(int)((long)B * H / 8 / 256), 256, 0, stream>>>(h0, h0bf,
                                                                  (long)B * H);
  transpose_conv<<<dim3(H / 32, D / 32), dim3(32, 8), 0, stream>>>(Wxh, WxhT, D, H);
  transpose_conv<<<dim3(H / 32, H / 32), dim3(32, 8), 0, stream>>>(Whh, WhhT, H, H);
  transpose_conv<<<dim3(Q / 32, H / 32), dim3(32, 8), 0, stream>>>(Whq, WhqT, H, Q);

  // --- Z = x @ W_xh + b_h  (all timesteps), bf16 into Hbuf ---
  gemm_bt_128<1><<<dim3(H / 128, MB / 128), 256, 0, stream>>>(
      x_bf, WxhT, bh, Hbuf, (int)MB, H, D);

  // --- entire recurrence in ONE persistent kernel ---
  rnn_persistent<<<256, 256, 0, stream>>>(h0bf, Hbuf, WhhT, ctr);

  // --- out = H @ W_hq + b_q  (fp32 straight to d_out) ---
  gemm_bt_128<0><<<dim3(Q / 128, MB / 128), 256, 0, stream>>>(
      Hbuf, WhqT, bq, out, (int)MB, Q, H);

  // --- final h (fp32) appended after (T*B, Q) block ---
  conv_bf16_f32<<<(int)((long)B * H / 256), 256, 0, stream>>>(
      Hbuf + (long)(T - 1) * B * H, out + MB * Q, (long)B * H);
}

// Round 4
// 3138.544 us; speedup vs baseline: 1.7125x; 1.7125x over previous
//
#include <hip/hip_runtime.h>
#include <hip/hip_bf16.h>

typedef __bf16 bf16_t;
typedef bf16_t bf16x8 __attribute__((ext_vector_type(8)));
typedef bf16_t bf16x4 __attribute__((ext_vector_type(4)));
typedef float f32x4 __attribute__((ext_vector_type(4)));

// ---------------------------------------------------------------------------
// async global -> LDS, 16B per lane (wave-uniform LDS base, HW adds lane*16)
// ---------------------------------------------------------------------------
__device__ __forceinline__ void load_lds16(const bf16_t* g, bf16_t* l) {
  __builtin_amdgcn_global_load_lds(
      (const __attribute__((address_space(1))) unsigned int*)g,
      (__attribute__((address_space(3))) unsigned int*)l,
      16, 0, 0);
}

// ---------------------------------------------------------------------------
__global__ void conv_f32_bf16(const float* __restrict__ src,
                              bf16_t* __restrict__ dst, long n) {
  long i = ((long)blockIdx.x * blockDim.x + threadIdx.x) * 8;
  if (i + 7 >= n) return;
  float4 a = *(const float4*)(src + i);
  float4 b = *(const float4*)(src + i + 4);
  bf16x8 v;
  v[0] = (bf16_t)a.x; v[1] = (bf16_t)a.y; v[2] = (bf16_t)a.z; v[3] = (bf16_t)a.w;
  v[4] = (bf16_t)b.x; v[5] = (bf16_t)b.y; v[6] = (bf16_t)b.z; v[7] = (bf16_t)b.w;
  *(bf16x8*)(dst + i) = v;
}

__global__ void conv_bf16_f32(const bf16_t* __restrict__ src,
                              float* __restrict__ dst, long n) {
  long i = (long)blockIdx.x * blockDim.x + threadIdx.x;
  if (i >= n) return;
  dst[i] = (float)src[i];
}

__global__ void transpose_conv(const float* __restrict__ src,
                               bf16_t* __restrict__ dst, int Ksrc, int Nsrc) {
  __shared__ float tile[32][33];
  int n0 = blockIdx.x * 32, k0 = blockIdx.y * 32;
  int tx = threadIdx.x, ty = threadIdx.y;  // (32, 8)
#pragma unroll
  for (int i = 0; i < 32; i += 8)
    tile[ty + i][tx] = src[(long)(k0 + ty + i) * Nsrc + n0 + tx];
  __syncthreads();
#pragma unroll
  for (int i = 0; i < 32; i += 8)
    dst[(long)(n0 + ty + i) * Ksrc + k0 + tx] = (bf16_t)tile[tx][ty + i];
}

// ---------------------------------------------------------------------------
// m97-style GEMM: D[M,N] = A[M,K] @ Bt[N,K]^T + bias
// ---------------------------------------------------------------------------
template <int STORE_MODE>
__global__ __launch_bounds__(256) void gemm_bt_128(
    const bf16_t* __restrict__ A, const bf16_t* __restrict__ Bt,
    const float* __restrict__ bias, void* __restrict__ Dout,
    int M, int N, int K) {
  __shared__ bf16_t As[128 * 32];
  __shared__ bf16_t Bs[128 * 32];
  const int tid = threadIdx.x;
  const int lane = tid & 63;
  const int w = tid >> 6;
  const int wr = w >> 1, wc = w & 1;
  const int m0 = blockIdx.y * 128, n0 = blockIdx.x * 128;

  f32x4 acc[4][4] = {};

  const int r0 = tid >> 2;
  const int kk = (tid & 3) * 8;
  const int fr = lane & 15;
  const int fk = (lane >> 4) * 8;

  for (int k0 = 0; k0 < K; k0 += 32) {
    load_lds16(A + (long)(m0 + r0) * K + k0 + kk, As + w * 512);
    load_lds16(A + (long)(m0 + 64 + r0) * K + k0 + kk, As + 2048 + w * 512);
    load_lds16(Bt + (long)(n0 + r0) * K + k0 + kk, Bs + w * 512);
    load_lds16(Bt + (long)(n0 + 64 + r0) * K + k0 + kk, Bs + 2048 + w * 512);
    asm volatile("s_waitcnt vmcnt(0)" ::: "memory");
    __syncthreads();

    bf16x8 af[4], bfx[4];
#pragma unroll
    for (int m = 0; m < 4; ++m)
      af[m] = *(const bf16x8*)&As[(wr * 64 + m * 16 + fr) * 32 + fk];
#pragma unroll
    for (int n = 0; n < 4; ++n)
      bfx[n] = *(const bf16x8*)&Bs[(wc * 64 + n * 16 + fr) * 32 + fk];
#pragma unroll
    for (int m = 0; m < 4; ++m)
#pragma unroll
      for (int n = 0; n < 4; ++n)
        acc[m][n] = __builtin_amdgcn_mfma_f32_16x16x32_bf16(af[m], bfx[n],
                                                            acc[m][n], 0, 0, 0);
    __syncthreads();
  }

  const int fq = lane >> 4;
#pragma unroll
  for (int m = 0; m < 4; ++m) {
#pragma unroll
    for (int n = 0; n < 4; ++n) {
      int col = n0 + wc * 64 + n * 16 + fr;
      float bv = bias[col];
#pragma unroll
      for (int r = 0; r < 4; ++r) {
        int row = m0 + wr * 64 + m * 16 + fq * 4 + r;
        float v = acc[m][n][r] + bv;
        if (STORE_MODE == 0)
          ((float*)Dout)[(long)row * N + col] = v;
        else
          ((bf16_t*)Dout)[(long)row * N + col] = (bf16_t)v;
      }
    }
  }
}

// ---------------------------------------------------------------------------
// Persistent recurrence: 256 WGs (1/CU), 256 thr (4 waves).
// WG gid: group g = gid&7 (row slab g*16..+16, maps to XCD g under round-robin
// dispatch), col tile i = gid>>3 (cols i*64..+64).  Wave w owns K-slab w*512.
// W_hh B-slice (64 cols x 512 K) pinned in 256 VGPRs via opaque asm.
// Sync: per-WG padded flag (64B apart). Producer: one release-store.
// Waiter: wave 0 polls its group's 32 flags in PARALLEL (flag per lane),
// __all(), one acquire fence. No contended RMW anywhere.
// ---------------------------------------------------------------------------
__global__ __launch_bounds__(256, 1) void rnn_persistent2(
    const bf16_t* __restrict__ h0,
    bf16_t* __restrict__ Hbuf,        // Z in, h out, (T,B,H) bf16
    const bf16_t* __restrict__ WhhT,  // (2048 cols, 2048 K) bf16
    unsigned int* __restrict__ flags) {  // 256 flags, 64B apart, pre-zeroed
  __shared__ float sred[4][1024];  // 16 KB

  const int tid = threadIdx.x, lane = tid & 63, w = tid >> 6;
  const int gid = blockIdx.x;
  const int g = gid & 7;    // row group (XCD under round-robin)
  const int i = gid >> 3;   // col tile 0..31
  const int m0 = g * 16, n0 = i * 64;
  const int H = 2048;
  const long BH = 128L * 2048;
  const int kb = w * 512;
  const int fr = lane & 15, fg = lane >> 4;

  // ---- preload W_hh slice (4 col-frags x 16 k-steps) and PIN in VGPRs ----
  bf16x8 bfrag[4][16];
#pragma unroll
  for (int n = 0; n < 4; ++n)
#pragma unroll
    for (int ks = 0; ks < 16; ++ks) {
      bfrag[n][ks] = *(const bf16x8*)(WhhT + (long)(n0 + n * 16 + fr) * H +
                                      kb + ks * 32 + fg * 8);
      f32x4 tmp = __builtin_bit_cast(f32x4, bfrag[n][ks]);
      asm volatile("" : "+v"(tmp));  // opaque: blocks rematerialization
      bfrag[n][ks] = __builtin_bit_cast(bf16x8, tmp);
    }

  // epilogue ownership: 4 contiguous cols per thread (16x64 tile = 1024)
  const int jj = tid * 4;
  const int zrow = jj >> 6, zcol = jj & 63;
  const long zoff = (long)(m0 + zrow) * H + n0 + zcol;

  unsigned int* myflag = flags + (g * 32 + i) * 16;
  const unsigned int* pollflag = flags + (g * 32 + (lane & 31)) * 16;

  for (int t = 0; t < 256; ++t) {
    const bf16_t* hp = (t == 0) ? h0 : Hbuf + (long)(t - 1) * BH;
    bf16_t* z = Hbuf + (long)t * BH;

    // prefetch Z (independent of producers)
    bf16x4 zv = *(const bf16x4*)(z + zoff);

    if (t > 0) {
      if (w == 0) {
        unsigned int v;
        do {
          v = __hip_atomic_load(pollflag, __ATOMIC_RELAXED,
                                __HIP_MEMORY_SCOPE_AGENT);
          if (__all(v >= (unsigned int)t)) break;
          __builtin_amdgcn_s_sleep(1);
        } while (true);
        __builtin_amdgcn_fence(__ATOMIC_ACQUIRE, "agent");
      }
      __syncthreads();
    }

    // ---- MFMA phase: A-frags direct from global ----
    const bf16_t* Ab = hp + (long)(m0 + fr) * H + kb + fg * 8;
    f32x4 acc[4] = {};
#pragma unroll
    for (int ks = 0; ks < 16; ++ks) {
      bf16x8 a = *(const bf16x8*)(Ab + ks * 32);
      acc[0] = __builtin_amdgcn_mfma_f32_16x16x32_bf16(a, bfrag[0][ks], acc[0], 0, 0, 0);
      acc[1] = __builtin_amdgcn_mfma_f32_16x16x32_bf16(a, bfrag[1][ks], acc[1], 0, 0, 0);
      acc[2] = __builtin_amdgcn_mfma_f32_16x16x32_bf16(a, bfrag[2][ks], acc[2], 0, 0, 0);
      acc[3] = __builtin_amdgcn_mfma_f32_16x16x32_bf16(a, bfrag[3][ks], acc[3], 0, 0, 0);
    }

    // ---- cross-wave K-reduction (K split 4x512) ----
#pragma unroll
    for (int n = 0; n < 4; ++n)
#pragma unroll
      for (int rr = 0; rr < 4; ++rr)
        sred[w][(fg * 4 + rr) * 64 + n * 16 + fr] = acc[n][rr];
    __syncthreads();

    bf16x4 o;
#pragma unroll
    for (int c4 = 0; c4 < 4; ++c4) {
      float s = sred[0][jj + c4] + sred[1][jj + c4] + sred[2][jj + c4] +
                sred[3][jj + c4];
      float v = s + (float)zv[c4];
      o[c4] = (bf16_t)(v > 0.f ? v : 0.f);
    }
    *(bf16x4*)(z + zoff) = o;

    // drain stores (compiler emits vmcnt(0) before s_barrier) + sred WAR guard
    __syncthreads();
    if (tid == 0)
      __hip_atomic_store(myflag, (unsigned int)(t + 1), __ATOMIC_RELEASE,
                         __HIP_MEMORY_SCOPE_AGENT);
  }
}

// ---------------------------------------------------------------------------
extern "C" void kernel_launch(void* const* d_in, const int* in_sizes, int n_in,
                              void* d_out, int out_size, void* d_ws,
                              size_t ws_size, hipStream_t stream) {
  const float* x   = (const float*)d_in[0];  // (T,B,D)
  const float* h0  = (const float*)d_in[1];  // (B,H)
  const float* Wxh = (const float*)d_in[2];  // (D,H)
  const float* Whh = (const float*)d_in[3];  // (H,H)
  const float* bh  = (const float*)d_in[4];  // (H,)
  const float* Whq = (const float*)d_in[5];  // (H,Q)
  const float* bq  = (const float*)d_in[6];  // (Q,)
  float* out = (float*)d_out;

  const int T = 256, B = 128, D = 1024, H = 2048, Q = 1024;
  const long MB = (long)T * B;  // 32768

  char* ws = (char*)d_ws;
  unsigned int* flags = (unsigned int*)ws;  ws += 256 * 64;  // padded flags
  bf16_t* x_bf = (bf16_t*)ws;  ws += MB * D * 2;             // 64 MiB
  bf16_t* Hbuf = (bf16_t*)ws;  ws += MB * H * 2;             // 128 MiB (Z->h)
  bf16_t* h0bf = (bf16_t*)ws;  ws += (long)B * H * 2;
  bf16_t* WxhT = (bf16_t*)ws;  ws += (long)H * D * 2;
  bf16_t* WhhT = (bf16_t*)ws;  ws += (long)H * H * 2;
  bf16_t* WhqT = (bf16_t*)ws;  ws += (long)Q * H * 2;

  hipMemsetAsync(flags, 0, 256 * 64, stream);

  // --- convert inputs to bf16 (weights transposed to N x K) ---
  conv_f32_bf16<<<(int)(MB * D / 8 / 256), 256, 0, stream>>>(x, x_bf, MB * D);
  conv_f32_bf16<<<(int)((long)B * H / 8 / 256), 256, 0, stream>>>(h0, h0bf,
                                                                  (long)B * H);
  transpose_conv<<<dim3(H / 32, D / 32), dim3(32, 8), 0, stream>>>(Wxh, WxhT, D, H);
  transpose_conv<<<dim3(H / 32, H / 32), dim3(32, 8), 0, stream>>>(Whh, WhhT, H, H);
  transpose_conv<<<dim3(Q / 32, H / 32), dim3(32, 8), 0, stream>>>(Whq, WhqT, H, Q);

  // --- Z = x @ W_xh + b_h  (all timesteps), bf16 into Hbuf ---
  gemm_bt_128<1><<<dim3(H / 128, MB / 128), 256, 0, stream>>>(
      x_bf, WxhT, bh, Hbuf, (int)MB, H, D);

  // --- entire recurrence in ONE persistent kernel ---
  rnn_persistent2<<<256, 256, 0, stream>>>(h0bf, Hbuf, WhhT, flags);

  // --- out = H @ W_hq + b_q  (fp32 straight to d_out) ---
  gemm_bt_128<0><<<dim3(Q / 128, MB / 128), 256, 0, stream>>>(
      Hbuf, WhqT, bq, out, (int)MB, Q, H);

  // --- final h (fp32) appended after (T*B, Q) block ---
  conv_bf16_f32<<<(int)((long)B * H / 256), 256, 0, stream>>>(
      Hbuf + (long)(T - 1) * B * H, out + MB * Q, (long)B * H);
}

// Round 5
// 2259.116 us; speedup vs baseline: 2.3792x; 1.3893x over previous
//
#include <hip/hip_runtime.h>
#include <hip/hip_bf16.h>

typedef __bf16 bf16_t;
typedef bf16_t bf16x8 __attribute__((ext_vector_type(8)));
typedef bf16_t bf16x4 __attribute__((ext_vector_type(4)));
typedef float f32x4 __attribute__((ext_vector_type(4)));
typedef float f32x2 __attribute__((ext_vector_type(2)));

// ---------------------------------------------------------------------------
// async global -> LDS, 16B per lane (wave-uniform LDS base, HW adds lane*16)
// ---------------------------------------------------------------------------
__device__ __forceinline__ void load_lds16(const bf16_t* g, bf16_t* l) {
  __builtin_amdgcn_global_load_lds(
      (const __attribute__((address_space(1))) unsigned int*)g,
      (__attribute__((address_space(3))) unsigned int*)l,
      16, 0, 0);
}

// ---------------------------------------------------------------------------
__global__ void conv_f32_bf16(const float* __restrict__ src,
                              bf16_t* __restrict__ dst, long n) {
  long i = ((long)blockIdx.x * blockDim.x + threadIdx.x) * 8;
  if (i + 7 >= n) return;
  float4 a = *(const float4*)(src + i);
  float4 b = *(const float4*)(src + i + 4);
  bf16x8 v;
  v[0] = (bf16_t)a.x; v[1] = (bf16_t)a.y; v[2] = (bf16_t)a.z; v[3] = (bf16_t)a.w;
  v[4] = (bf16_t)b.x; v[5] = (bf16_t)b.y; v[6] = (bf16_t)b.z; v[7] = (bf16_t)b.w;
  *(bf16x8*)(dst + i) = v;
}

__global__ void conv_bf16_f32(const bf16_t* __restrict__ src,
                              float* __restrict__ dst, long n) {
  long i = (long)blockIdx.x * blockDim.x + threadIdx.x;
  if (i >= n) return;
  dst[i] = (float)src[i];
}

__global__ void transpose_conv(const float* __restrict__ src,
                               bf16_t* __restrict__ dst, int Ksrc, int Nsrc) {
  __shared__ float tile[32][33];
  int n0 = blockIdx.x * 32, k0 = blockIdx.y * 32;
  int tx = threadIdx.x, ty = threadIdx.y;  // (32, 8)
#pragma unroll
  for (int i = 0; i < 32; i += 8)
    tile[ty + i][tx] = src[(long)(k0 + ty + i) * Nsrc + n0 + tx];
  __syncthreads();
#pragma unroll
  for (int i = 0; i < 32; i += 8)
    dst[(long)(n0 + ty + i) * Ksrc + k0 + tx] = (bf16_t)tile[tx][ty + i];
}

// ---------------------------------------------------------------------------
// m97-style GEMM: D[M,N] = A[M,K] @ Bt[N,K]^T + bias
// ---------------------------------------------------------------------------
template <int STORE_MODE>
__global__ __launch_bounds__(256) void gemm_bt_128(
    const bf16_t* __restrict__ A, const bf16_t* __restrict__ Bt,
    const float* __restrict__ bias, void* __restrict__ Dout,
    int M, int N, int K) {
  __shared__ bf16_t As[128 * 32];
  __shared__ bf16_t Bs[128 * 32];
  const int tid = threadIdx.x;
  const int lane = tid & 63;
  const int w = tid >> 6;
  const int wr = w >> 1, wc = w & 1;
  const int m0 = blockIdx.y * 128, n0 = blockIdx.x * 128;

  f32x4 acc[4][4] = {};

  const int r0 = tid >> 2;
  const int kk = (tid & 3) * 8;
  const int fr = lane & 15;
  const int fk = (lane >> 4) * 8;

  for (int k0 = 0; k0 < K; k0 += 32) {
    load_lds16(A + (long)(m0 + r0) * K + k0 + kk, As + w * 512);
    load_lds16(A + (long)(m0 + 64 + r0) * K + k0 + kk, As + 2048 + w * 512);
    load_lds16(Bt + (long)(n0 + r0) * K + k0 + kk, Bs + w * 512);
    load_lds16(Bt + (long)(n0 + 64 + r0) * K + k0 + kk, Bs + 2048 + w * 512);
    asm volatile("s_waitcnt vmcnt(0)" ::: "memory");
    __syncthreads();

    bf16x8 af[4], bfx[4];
#pragma unroll
    for (int m = 0; m < 4; ++m)
      af[m] = *(const bf16x8*)&As[(wr * 64 + m * 16 + fr) * 32 + fk];
#pragma unroll
    for (int n = 0; n < 4; ++n)
      bfx[n] = *(const bf16x8*)&Bs[(wc * 64 + n * 16 + fr) * 32 + fk];
#pragma unroll
    for (int m = 0; m < 4; ++m)
#pragma unroll
      for (int n = 0; n < 4; ++n)
        acc[m][n] = __builtin_amdgcn_mfma_f32_16x16x32_bf16(af[m], bfx[n],
                                                            acc[m][n], 0, 0, 0);
    __syncthreads();
  }

  const int fq = lane >> 4;
#pragma unroll
  for (int m = 0; m < 4; ++m) {
#pragma unroll
    for (int n = 0; n < 4; ++n) {
      int col = n0 + wc * 64 + n * 16 + fr;
      float bv = bias[col];
#pragma unroll
      for (int r = 0; r < 4; ++r) {
        int row = m0 + wr * 64 + m * 16 + fq * 4 + r;
        float v = acc[m][n][r] + bv;
        if (STORE_MODE == 0)
          ((float*)Dout)[(long)row * N + col] = v;
        else
          ((bf16_t*)Dout)[(long)row * N + col] = (bf16_t)v;
      }
    }
  }
}

// ---------------------------------------------------------------------------
// Persistent recurrence, fence-free coherence.
// 256 WGs (1/CU), 256 thr (4 waves). gid -> x=gid&7 (XCD), y=gid>>3;
// g=y>>2 (row slab g*16..+16), i=x+8*(y&3) (col tile i*64..+64).
// W cols [n0,n0+32) staged in LDS (128KB, [k16][col] chunk layout, once);
// cols [n0+32,n0+64) streamed from L2 (hot forever: NO fences -> no L2 inv).
// h handoff: stores/loads use sc0 sc1 (bypass L1/L2, coherent at L3);
// producer: vmcnt(0) then relaxed agent flag store; consumer: relaxed agent
// flag poll (wave w polls only its 8 K-slab producers), then asm-blob loads.
// ---------------------------------------------------------------------------
__global__ __launch_bounds__(256, 1) void rnn_persistent3(
    const bf16_t* __restrict__ h0,
    bf16_t* __restrict__ Hbuf,        // Z in, h out, (T,B,H) bf16
    const bf16_t* __restrict__ WhhT,  // (2048 cols, 2048 K) bf16
    unsigned int* __restrict__ flags) {  // 256 flags, 64B apart, pre-zeroed
  __shared__ bf16_t Wlds[65536];       // 128 KB: chunk (k16)*256 + col*8
  __shared__ float sred[4][16 * 68];   // padded stride 68 (17.4 KB)

  const int tid = threadIdx.x, lane = tid & 63, w = tid >> 6;
  const int gid = blockIdx.x;
  const int x = gid & 7, y = gid >> 3;
  const int g = y >> 2;               // row group 0..7
  const int i = x + 8 * (y & 3);      // col tile 0..31 (i%8 == XCD)
  const int m0 = g * 16, n0 = i * 64;
  const int H = 2048;
  const long BH = 128L * 2048;
  const int kb = w * 512;             // wave K-slab
  const int fr = lane & 15, fg = lane >> 4;
  const int kq = w * 64 + fg;         // k16 base for this wave/lane

  // ---- stage W cols [n0, n0+32) into LDS (once) ----
  for (int it = 0; it < 4; ++it) {
    int col = it * 8 + (tid >> 5);
    const bf16_t* gsrc = WhhT + (long)(n0 + col) * H + (tid & 31) * 8;
#pragma unroll
    for (int jx = 0; jx < 8; ++jx) {
      bf16x8 v = *(const bf16x8*)(gsrc + jx * 256);
      int k16 = (tid & 31) + 32 * jx;
      *(bf16x8*)&Wlds[k16 * 256 + col * 8] = v;
    }
  }
  __syncthreads();

  const bf16_t* Wg2 = WhhT + (long)(n0 + 32 + fr) * H + kb + fg * 8;
  const bf16_t* Wg3 = Wg2 + (long)16 * H;

  const int jj = tid * 4;
  const int zrow = jj >> 6, zcol = jj & 63;
  const long zoff = (long)(m0 + zrow) * H + n0 + zcol;
  const int sidx = zrow * 68 + zcol;

  unsigned int* myflag = flags + ((g * 32 + i) << 4);
  const unsigned int* pollflag = flags + ((g * 32 + w * 8 + (lane & 7)) << 4);

  for (int t = 0; t < 256; ++t) {
    const bf16_t* hp = (t == 0) ? h0 : Hbuf + (long)(t - 1) * BH;
    bf16_t* z = Hbuf + (long)t * BH;

    // Z prefetch (normal cached; independent of producers)
    bf16x4 zv = *(const bf16x4*)(z + zoff);

    if (t > 0) {
      unsigned int v;
      do {
        v = __hip_atomic_load(pollflag, __ATOMIC_RELAXED,
                              __HIP_MEMORY_SCOPE_AGENT);
        if (__all(v >= (unsigned int)t)) break;
        __builtin_amdgcn_s_sleep(1);
      } while (true);
    }

    // ---- A-frags: 16 coherent (L2-bypass) loads, one blob, one drain ----
    const bf16_t* Ab = hp + (long)(m0 + fr) * H + kb + fg * 8;
    f32x4 a0, a1, a2, a3, a4, a5, a6, a7, a8, a9, a10, a11, a12, a13, a14, a15;
    asm volatile(
        "global_load_dwordx4 %0, %16, off sc0 sc1\n\t"
        "global_load_dwordx4 %1, %16, off offset:64 sc0 sc1\n\t"
        "global_load_dwordx4 %2, %16, off offset:128 sc0 sc1\n\t"
        "global_load_dwordx4 %3, %16, off offset:192 sc0 sc1\n\t"
        "global_load_dwordx4 %4, %16, off offset:256 sc0 sc1\n\t"
        "global_load_dwordx4 %5, %16, off offset:320 sc0 sc1\n\t"
        "global_load_dwordx4 %6, %16, off offset:384 sc0 sc1\n\t"
        "global_load_dwordx4 %7, %16, off offset:448 sc0 sc1\n\t"
        "global_load_dwordx4 %8, %16, off offset:512 sc0 sc1\n\t"
        "global_load_dwordx4 %9, %16, off offset:576 sc0 sc1\n\t"
        "global_load_dwordx4 %10, %16, off offset:640 sc0 sc1\n\t"
        "global_load_dwordx4 %11, %16, off offset:704 sc0 sc1\n\t"
        "global_load_dwordx4 %12, %16, off offset:768 sc0 sc1\n\t"
        "global_load_dwordx4 %13, %16, off offset:832 sc0 sc1\n\t"
        "global_load_dwordx4 %14, %16, off offset:896 sc0 sc1\n\t"
        "global_load_dwordx4 %15, %16, off offset:960 sc0 sc1\n\t"
        "s_waitcnt vmcnt(0)"
        : "=&v"(a0), "=&v"(a1), "=&v"(a2), "=&v"(a3), "=&v"(a4), "=&v"(a5),
          "=&v"(a6), "=&v"(a7), "=&v"(a8), "=&v"(a9), "=&v"(a10), "=&v"(a11),
          "=&v"(a12), "=&v"(a13), "=&v"(a14), "=&v"(a15)
        : "v"(Ab)
        : "memory");
    __builtin_amdgcn_sched_barrier(0);  // rule #18: keep uses after the wait

    f32x4 acc[4] = {};
#define STEP(ks, A)                                                           \
  {                                                                           \
    bf16x8 w0 = *(const bf16x8*)&Wlds[(kq + (ks) * 4) * 256 + fr * 8];        \
    bf16x8 w1 = *(const bf16x8*)&Wlds[(kq + (ks) * 4) * 256 + fr * 8 + 128];  \
    bf16x8 g2 = *(const bf16x8*)(Wg2 + (ks) * 32);                            \
    bf16x8 g3 = *(const bf16x8*)(Wg3 + (ks) * 32);                            \
    bf16x8 av = __builtin_bit_cast(bf16x8, A);                                \
    acc[0] = __builtin_amdgcn_mfma_f32_16x16x32_bf16(av, w0, acc[0], 0, 0, 0);\
    acc[1] = __builtin_amdgcn_mfma_f32_16x16x32_bf16(av, w1, acc[1], 0, 0, 0);\
    acc[2] = __builtin_amdgcn_mfma_f32_16x16x32_bf16(av, g2, acc[2], 0, 0, 0);\
    acc[3] = __builtin_amdgcn_mfma_f32_16x16x32_bf16(av, g3, acc[3], 0, 0, 0);\
  }
    STEP(0, a0)  STEP(1, a1)  STEP(2, a2)  STEP(3, a3)
    STEP(4, a4)  STEP(5, a5)  STEP(6, a6)  STEP(7, a7)
    STEP(8, a8)  STEP(9, a9)  STEP(10, a10) STEP(11, a11)
    STEP(12, a12) STEP(13, a13) STEP(14, a14) STEP(15, a15)
#undef STEP

    // ---- cross-wave K-reduction (padded stride 68) ----
#pragma unroll
    for (int n = 0; n < 4; ++n)
#pragma unroll
      for (int rr = 0; rr < 4; ++rr)
        sred[w][(fg * 4 + rr) * 68 + n * 16 + fr] = acc[n][rr];
    __syncthreads();

    // ---- reduce 4 waves + Z + relu; coherent 8B store ----
    f32x4 r = *(const f32x4*)&sred[0][sidx];
    {
      f32x4 r1 = *(const f32x4*)&sred[1][sidx];
      f32x4 r2 = *(const f32x4*)&sred[2][sidx];
      f32x4 r3 = *(const f32x4*)&sred[3][sidx];
      r = r + r1 + r2 + r3;
    }
    bf16x4 o;
#pragma unroll
    for (int c4 = 0; c4 < 4; ++c4) {
      float v = r[c4] + (float)zv[c4];
      o[c4] = (bf16_t)(v > 0.f ? v : 0.f);
    }
    {
      f32x2 ov = __builtin_bit_cast(f32x2, o);
      const bf16_t* zp = z + zoff;
      asm volatile("global_store_dwordx2 %0, %1, off sc0 sc1" ::"v"(zp),
                   "v"(ov)
                   : "memory");
    }
    asm volatile("s_waitcnt vmcnt(0)" ::: "memory");
    __syncthreads();  // all waves' stores drained; sred WAR-safe
    if (tid == 0)
      __hip_atomic_store(myflag, (unsigned int)(t + 1), __ATOMIC_RELAXED,
                         __HIP_MEMORY_SCOPE_AGENT);
  }
}

// ---------------------------------------------------------------------------
extern "C" void kernel_launch(void* const* d_in, const int* in_sizes, int n_in,
                              void* d_out, int out_size, void* d_ws,
                              size_t ws_size, hipStream_t stream) {
  const float* x   = (const float*)d_in[0];  // (T,B,D)
  const float* h0  = (const float*)d_in[1];  // (B,H)
  const float* Wxh = (const float*)d_in[2];  // (D,H)
  const float* Whh = (const float*)d_in[3];  // (H,H)
  const float* bh  = (const float*)d_in[4];  // (H,)
  const float* Whq = (const float*)d_in[5];  // (H,Q)
  const float* bq  = (const float*)d_in[6];  // (Q,)
  float* out = (float*)d_out;

  const int T = 256, B = 128, D = 1024, H = 2048, Q = 1024;
  const long MB = (long)T * B;  // 32768

  char* ws = (char*)d_ws;
  unsigned int* flags = (unsigned int*)ws;  ws += 256 * 64;  // padded flags
  bf16_t* x_bf = (bf16_t*)ws;  ws += MB * D * 2;             // 64 MiB
  bf16_t* Hbuf = (bf16_t*)ws;  ws += MB * H * 2;             // 128 MiB (Z->h)
  bf16_t* h0bf = (bf16_t*)ws;  ws += (long)B * H * 2;
  bf16_t* WxhT = (bf16_t*)ws;  ws += (long)H * D * 2;
  bf16_t* WhhT = (bf16_t*)ws;  ws += (long)H * H * 2;
  bf16_t* WhqT = (bf16_t*)ws;  ws += (long)Q * H * 2;

  hipMemsetAsync(flags, 0, 256 * 64, stream);

  // --- convert inputs to bf16 (weights transposed to N x K) ---
  conv_f32_bf16<<<(int)(MB * D / 8 / 256), 256, 0, stream>>>(x, x_bf, MB * D);
  conv_f32_bf16<<<(int)((long)B * H / 8 / 256), 256, 0, stream>>>(h0, h0bf,
                                                                  (long)B * H);
  transpose_conv<<<dim3(H / 32, D / 32), dim3(32, 8), 0, stream>>>(Wxh, WxhT, D, H);
  transpose_conv<<<dim3(H / 32, H / 32), dim3(32, 8), 0, stream>>>(Whh, WhhT, H, H);
  transpose_conv<<<dim3(Q / 32, H / 32), dim3(32, 8), 0, stream>>>(Whq, WhqT, H, Q);

  // --- Z = x @ W_xh + b_h  (all timesteps), bf16 into Hbuf ---
  gemm_bt_128<1><<<dim3(H / 128, MB / 128), 256, 0, stream>>>(
      x_bf, WxhT, bh, Hbuf, (int)MB, H, D);

  // --- entire recurrence in ONE persistent, fence-free kernel ---
  rnn_persistent3<<<256, 256, 0, stream>>>(h0bf, Hbuf, WhhT, flags);

  // --- out = H @ W_hq + b_q  (fp32 straight to d_out) ---
  gemm_bt_128<0><<<dim3(Q / 128, MB / 128), 256, 0, stream>>>(
      Hbuf, WhqT, bq, out, (int)MB, Q, H);

  // --- final h (fp32) appended after (T*B, Q) block ---
  conv_bf16_f32<<<(int)((long)B * H / 256), 256, 0, stream>>>(
      Hbuf + (long)(T - 1) * B * H, out + MB * Q, (long)B * H);
}

// Round 6
// 1895.221 us; speedup vs baseline: 2.8360x; 1.1920x over previous
//
#include <hip/hip_runtime.h>
#include <hip/hip_bf16.h>

typedef __bf16 bf16_t;
typedef bf16_t bf16x8 __attribute__((ext_vector_type(8)));
typedef bf16_t bf16x4 __attribute__((ext_vector_type(4)));
typedef float f32x4 __attribute__((ext_vector_type(4)));
typedef float f32x2 __attribute__((ext_vector_type(2)));

// ---------------------------------------------------------------------------
// async global -> LDS, 16B per lane (wave-uniform LDS base, HW adds lane*16)
// ---------------------------------------------------------------------------
__device__ __forceinline__ void load_lds16(const bf16_t* g, bf16_t* l) {
  __builtin_amdgcn_global_load_lds(
      (const __attribute__((address_space(1))) unsigned int*)g,
      (__attribute__((address_space(3))) unsigned int*)l,
      16, 0, 0);
}

// ---------------------------------------------------------------------------
__global__ void conv_f32_bf16(const float* __restrict__ src,
                              bf16_t* __restrict__ dst, long n) {
  long i = ((long)blockIdx.x * blockDim.x + threadIdx.x) * 8;
  if (i + 7 >= n) return;
  float4 a = *(const float4*)(src + i);
  float4 b = *(const float4*)(src + i + 4);
  bf16x8 v;
  v[0] = (bf16_t)a.x; v[1] = (bf16_t)a.y; v[2] = (bf16_t)a.z; v[3] = (bf16_t)a.w;
  v[4] = (bf16_t)b.x; v[5] = (bf16_t)b.y; v[6] = (bf16_t)b.z; v[7] = (bf16_t)b.w;
  *(bf16x8*)(dst + i) = v;
}

__global__ void conv_bf16_f32(const bf16_t* __restrict__ src,
                              float* __restrict__ dst, long n) {
  long i = (long)blockIdx.x * blockDim.x + threadIdx.x;
  if (i >= n) return;
  dst[i] = (float)src[i];
}

__global__ void transpose_conv(const float* __restrict__ src,
                               bf16_t* __restrict__ dst, int Ksrc, int Nsrc) {
  __shared__ float tile[32][33];
  int n0 = blockIdx.x * 32, k0 = blockIdx.y * 32;
  int tx = threadIdx.x, ty = threadIdx.y;  // (32, 8)
#pragma unroll
  for (int i = 0; i < 32; i += 8)
    tile[ty + i][tx] = src[(long)(k0 + ty + i) * Nsrc + n0 + tx];
  __syncthreads();
#pragma unroll
  for (int i = 0; i < 32; i += 8)
    dst[(long)(n0 + ty + i) * Ksrc + k0 + tx] = (bf16_t)tile[tx][ty + i];
}

// ---------------------------------------------------------------------------
// m97-style GEMM: D[M,N] = A[M,K] @ Bt[N,K]^T + bias
// ---------------------------------------------------------------------------
template <int STORE_MODE>
__global__ __launch_bounds__(256) void gemm_bt_128(
    const bf16_t* __restrict__ A, const bf16_t* __restrict__ Bt,
    const float* __restrict__ bias, void* __restrict__ Dout,
    int M, int N, int K) {
  __shared__ bf16_t As[128 * 32];
  __shared__ bf16_t Bs[128 * 32];
  const int tid = threadIdx.x;
  const int lane = tid & 63;
  const int w = tid >> 6;
  const int wr = w >> 1, wc = w & 1;
  const int m0 = blockIdx.y * 128, n0 = blockIdx.x * 128;

  f32x4 acc[4][4] = {};

  const int r0 = tid >> 2;
  const int kk = (tid & 3) * 8;
  const int fr = lane & 15;
  const int fk = (lane >> 4) * 8;

  for (int k0 = 0; k0 < K; k0 += 32) {
    load_lds16(A + (long)(m0 + r0) * K + k0 + kk, As + w * 512);
    load_lds16(A + (long)(m0 + 64 + r0) * K + k0 + kk, As + 2048 + w * 512);
    load_lds16(Bt + (long)(n0 + r0) * K + k0 + kk, Bs + w * 512);
    load_lds16(Bt + (long)(n0 + 64 + r0) * K + k0 + kk, Bs + 2048 + w * 512);
    asm volatile("s_waitcnt vmcnt(0)" ::: "memory");
    __syncthreads();

    bf16x8 af[4], bfx[4];
#pragma unroll
    for (int m = 0; m < 4; ++m)
      af[m] = *(const bf16x8*)&As[(wr * 64 + m * 16 + fr) * 32 + fk];
#pragma unroll
    for (int n = 0; n < 4; ++n)
      bfx[n] = *(const bf16x8*)&Bs[(wc * 64 + n * 16 + fr) * 32 + fk];
#pragma unroll
    for (int m = 0; m < 4; ++m)
#pragma unroll
      for (int n = 0; n < 4; ++n)
        acc[m][n] = __builtin_amdgcn_mfma_f32_16x16x32_bf16(af[m], bfx[n],
                                                            acc[m][n], 0, 0, 0);
    __syncthreads();
  }

  const int fq = lane >> 4;
#pragma unroll
  for (int m = 0; m < 4; ++m) {
#pragma unroll
    for (int n = 0; n < 4; ++n) {
      int col = n0 + wc * 64 + n * 16 + fr;
      float bv = bias[col];
#pragma unroll
      for (int r = 0; r < 4; ++r) {
        int row = m0 + wr * 64 + m * 16 + fq * 4 + r;
        float v = acc[m][n][r] + bv;
        if (STORE_MODE == 0)
          ((float*)Dout)[(long)row * N + col] = v;
        else
          ((bf16_t*)Dout)[(long)row * N + col] = (bf16_t)v;
      }
    }
  }
}

// ---------------------------------------------------------------------------
// Persistent recurrence, fence-free, ALL-W-in-LDS.
// 256 WGs (1/CU), 256 thr (4 waves).  Tile 32 rows x 32 cols.
// gid bits: a=gid&1, g=(gid>>1)&3, s=gid>>3  ->  group g (rows g*32..+32)
// on XCD pair {2g,2g+1}; col tile i = a*32+s (cols i*32..+32).
// W slice (32 cols x 2048 K, 128 KB) staged in LDS once -> ZERO W traffic/step.
// Wave w owns K-slab w*512.  Per step: A-frags via sc0 loads (L2-cacheable;
// safe: every Hbuf address is written once via sc0sc1 write-through, Z
// prefetch is sc0sc1 so no pre-store line is ever L2-cached), 64 MFMA,
// LDS cross-wave K-reduce, fused Z+ReLU, sc0sc1 store, flag.
// ---------------------------------------------------------------------------
__global__ __launch_bounds__(256, 1) void rnn_persistent4(
    const bf16_t* __restrict__ h0,
    bf16_t* __restrict__ Hbuf,        // Z in, h out, (T,B,H) bf16
    const bf16_t* __restrict__ WhhT,  // (2048 cols, 2048 K) bf16
    unsigned int* __restrict__ flags) {  // 256 flags, 64B apart, pre-zeroed
  __shared__ bf16_t Wlds[65536];       // 128 KB: elem ((k>>3)*32+col)*8 + k&7
  __shared__ float sred[4][32 * 36];   // 18.4 KB, padded stride 36

  const int tid = threadIdx.x, lane = tid & 63, w = tid >> 6;
  const int gid = blockIdx.x;
  const int g = (gid >> 1) & 3;                 // row group 0..3 (XCD pair 2g,2g+1)
  const int i = ((gid & 1) << 5) | (gid >> 3);  // col tile 0..63
  const int m0 = g * 32, n0 = i * 32;
  const int H = 2048;
  const long BH = 128L * 2048;
  const int kb = w * 512;             // wave K-slab
  const int fr = lane & 15, fg = lane >> 4;
  const int w64 = w * 64;

  // ---- stage W cols [n0, n0+32) into LDS (once) ----
  {
    const int scol = tid >> 3;          // 0..31
    const int sk = (tid & 7) * 8;       // k offset in 64-chunk
    const bf16_t* gsrc = WhhT + (long)(n0 + scol) * H + sk;
#pragma unroll 4
    for (int j = 0; j < 32; ++j) {
      bf16x8 v = *(const bf16x8*)(gsrc + j * 64);
      int k8 = j * 8 + (tid & 7);
      *(bf16x8*)&Wlds[(k8 * 32 + scol) * 8] = v;
    }
  }
  __syncthreads();

  // epilogue ownership: 4 contiguous cols per thread (32x32 tile = 1024)
  const int jj = tid * 4;
  const int zrow = jj >> 5, zcol = jj & 31;
  const long zoff = (long)(m0 + zrow) * H + n0 + zcol;
  const int sidx = zrow * 36 + zcol;

  unsigned int* myflag = flags + ((g * 64 + i) << 4);
  const unsigned int* pollflag = flags + ((g * 64 + w * 16 + (lane & 15)) << 4);

  for (int t = 0; t < 256; ++t) {
    const bf16_t* hp = (t == 0) ? h0 : Hbuf + (long)(t - 1) * BH;
    bf16_t* z = Hbuf + (long)t * BH;

    // Z prefetch: sc0 sc1 (no L2 allocation of not-yet-final lines)
    f32x2 zvr;
    {
      const bf16_t* zp = z + zoff;
      asm volatile("global_load_dwordx2 %0, %1, off sc0 sc1"
                   : "=v"(zvr)
                   : "v"(zp)
                   : "memory");
    }

    if (t > 0) {
      unsigned int v;
      do {
        v = __hip_atomic_load(pollflag, __ATOMIC_RELAXED,
                              __HIP_MEMORY_SCOPE_AGENT);
        if (__all(v >= (unsigned int)t)) break;
        __builtin_amdgcn_s_sleep(1);
      } while (true);
    }

    // ---- A-frags: rows lo (fr) and hi (16+fr), sc0 (L2-cacheable) ----
    const bf16_t* Ab0 = hp + (long)(m0 + fr) * H + kb + fg * 8;
    const bf16_t* Ab1 = Ab0 + (long)16 * H;
    f32x4 a0, a1, a2, a3, a4, a5, a6, a7, a8, a9, a10, a11, a12, a13, a14, a15;
    f32x4 c0, c1, c2, c3, c4, c5, c6, c7, c8, c9, c10, c11, c12, c13, c14, c15;
#define ABLOB(base)                                                           \
  "global_load_dwordx4 %0, %16, off sc0\n\t"                                  \
  "global_load_dwordx4 %1, %16, off offset:64 sc0\n\t"                        \
  "global_load_dwordx4 %2, %16, off offset:128 sc0\n\t"                       \
  "global_load_dwordx4 %3, %16, off offset:192 sc0\n\t"                       \
  "global_load_dwordx4 %4, %16, off offset:256 sc0\n\t"                       \
  "global_load_dwordx4 %5, %16, off offset:320 sc0\n\t"                       \
  "global_load_dwordx4 %6, %16, off offset:384 sc0\n\t"                       \
  "global_load_dwordx4 %7, %16, off offset:448 sc0\n\t"                       \
  "global_load_dwordx4 %8, %16, off offset:512 sc0\n\t"                       \
  "global_load_dwordx4 %9, %16, off offset:576 sc0\n\t"                       \
  "global_load_dwordx4 %10, %16, off offset:640 sc0\n\t"                      \
  "global_load_dwordx4 %11, %16, off offset:704 sc0\n\t"                      \
  "global_load_dwordx4 %12, %16, off offset:768 sc0\n\t"                      \
  "global_load_dwordx4 %13, %16, off offset:832 sc0\n\t"                      \
  "global_load_dwordx4 %14, %16, off offset:896 sc0\n\t"                      \
  "global_load_dwordx4 %15, %16, off offset:960 sc0"
    asm volatile(ABLOB(Ab0)
                 : "=&v"(a0), "=&v"(a1), "=&v"(a2), "=&v"(a3), "=&v"(a4),
                   "=&v"(a5), "=&v"(a6), "=&v"(a7), "=&v"(a8), "=&v"(a9),
                   "=&v"(a10), "=&v"(a11), "=&v"(a12), "=&v"(a13), "=&v"(a14),
                   "=&v"(a15)
                 : "v"(Ab0)
                 : "memory");
    asm volatile(ABLOB(Ab1)
                 : "=&v"(c0), "=&v"(c1), "=&v"(c2), "=&v"(c3), "=&v"(c4),
                   "=&v"(c5), "=&v"(c6), "=&v"(c7), "=&v"(c8), "=&v"(c9),
                   "=&v"(c10), "=&v"(c11), "=&v"(c12), "=&v"(c13), "=&v"(c14),
                   "=&v"(c15)
                 : "v"(Ab1)
                 : "memory");
#undef ABLOB

    f32x4 acc00 = {}, acc01 = {}, acc10 = {}, acc11 = {};
#define STEPX(ks, A, ACC0, ACC1)                                              \
  {                                                                           \
    bf16x8 w0 = *(const bf16x8*)&Wlds[((w64 + (ks) * 4 + fg) * 32 + fr) * 8]; \
    bf16x8 w1 =                                                               \
        *(const bf16x8*)&Wlds[((w64 + (ks) * 4 + fg) * 32 + 16 + fr) * 8];    \
    bf16x8 av = __builtin_bit_cast(bf16x8, A);                                \
    ACC0 = __builtin_amdgcn_mfma_f32_16x16x32_bf16(av, w0, ACC0, 0, 0, 0);    \
    ACC1 = __builtin_amdgcn_mfma_f32_16x16x32_bf16(av, w1, ACC1, 0, 0, 0);    \
  }
    asm volatile("s_waitcnt vmcnt(16)" ::: "memory");
    __builtin_amdgcn_sched_barrier(0);
    STEPX(0, a0, acc00, acc01)   STEPX(1, a1, acc00, acc01)
    STEPX(2, a2, acc00, acc01)   STEPX(3, a3, acc00, acc01)
    STEPX(4, a4, acc00, acc01)   STEPX(5, a5, acc00, acc01)
    STEPX(6, a6, acc00, acc01)   STEPX(7, a7, acc00, acc01)
    STEPX(8, a8, acc00, acc01)   STEPX(9, a9, acc00, acc01)
    STEPX(10, a10, acc00, acc01) STEPX(11, a11, acc00, acc01)
    STEPX(12, a12, acc00, acc01) STEPX(13, a13, acc00, acc01)
    STEPX(14, a14, acc00, acc01) STEPX(15, a15, acc00, acc01)
    asm volatile("s_waitcnt vmcnt(0)" ::: "memory");
    __builtin_amdgcn_sched_barrier(0);
    STEPX(0, c0, acc10, acc11)   STEPX(1, c1, acc10, acc11)
    STEPX(2, c2, acc10, acc11)   STEPX(3, c3, acc10, acc11)
    STEPX(4, c4, acc10, acc11)   STEPX(5, c5, acc10, acc11)
    STEPX(6, c6, acc10, acc11)   STEPX(7, c7, acc10, acc11)
    STEPX(8, c8, acc10, acc11)   STEPX(9, c9, acc10, acc11)
    STEPX(10, c10, acc10, acc11) STEPX(11, c11, acc10, acc11)
    STEPX(12, c12, acc10, acc11) STEPX(13, c13, acc10, acc11)
    STEPX(14, c14, acc10, acc11) STEPX(15, c15, acc10, acc11)
#undef STEPX

    // ---- cross-wave K-reduction (padded stride 36) ----
#pragma unroll
    for (int rr = 0; rr < 4; ++rr) {
      sred[w][(fg * 4 + rr) * 36 + fr] = acc00[rr];
      sred[w][(fg * 4 + rr) * 36 + 16 + fr] = acc01[rr];
      sred[w][(16 + fg * 4 + rr) * 36 + fr] = acc10[rr];
      sred[w][(16 + fg * 4 + rr) * 36 + 16 + fr] = acc11[rr];
    }
    __syncthreads();

    // ---- reduce 4 waves + Z + relu; sc0sc1 8B store ----
    f32x4 r = *(const f32x4*)&sred[0][sidx];
    {
      f32x4 r1 = *(const f32x4*)&sred[1][sidx];
      f32x4 r2 = *(const f32x4*)&sred[2][sidx];
      f32x4 r3 = *(const f32x4*)&sred[3][sidx];
      r = r + r1 + r2 + r3;
    }
    bf16x4 zv = __builtin_bit_cast(bf16x4, zvr);
    bf16x4 o;
#pragma unroll
    for (int c4 = 0; c4 < 4; ++c4) {
      float v = r[c4] + (float)zv[c4];
      o[c4] = (bf16_t)(v > 0.f ? v : 0.f);
    }
    {
      f32x2 ov = __builtin_bit_cast(f32x2, o);
      const bf16_t* zp = z + zoff;
      asm volatile("global_store_dwordx2 %0, %1, off sc0 sc1" ::"v"(zp),
                   "v"(ov)
                   : "memory");
    }
    asm volatile("s_waitcnt vmcnt(0)" ::: "memory");
    __syncthreads();  // all waves' stores drained; sred WAR-safe
    if (tid == 0)
      __hip_atomic_store(myflag, (unsigned int)(t + 1), __ATOMIC_RELAXED,
                         __HIP_MEMORY_SCOPE_AGENT);
  }
}

// ---------------------------------------------------------------------------
extern "C" void kernel_launch(void* const* d_in, const int* in_sizes, int n_in,
                              void* d_out, int out_size, void* d_ws,
                              size_t ws_size, hipStream_t stream) {
  const float* x   = (const float*)d_in[0];  // (T,B,D)
  const float* h0  = (const float*)d_in[1];  // (B,H)
  const float* Wxh = (const float*)d_in[2];  // (D,H)
  const float* Whh = (const float*)d_in[3];  // (H,H)
  const float* bh  = (const float*)d_in[4];  // (H,)
  const float* Whq = (const float*)d_in[5];  // (H,Q)
  const float* bq  = (const float*)d_in[6];  // (Q,)
  float* out = (float*)d_out;

  const int T = 256, B = 128, D = 1024, H = 2048, Q = 1024;
  const long MB = (long)T * B;  // 32768

  char* ws = (char*)d_ws;
  unsigned int* flags = (unsigned int*)ws;  ws += 256 * 64;  // padded flags
  bf16_t* x_bf = (bf16_t*)ws;  ws += MB * D * 2;             // 64 MiB
  bf16_t* Hbuf = (bf16_t*)ws;  ws += MB * H * 2;             // 128 MiB (Z->h)
  bf16_t* h0bf = (bf16_t*)ws;  ws += (long)B * H * 2;
  bf16_t* WxhT = (bf16_t*)ws;  ws += (long)H * D * 2;
  bf16_t* WhhT = (bf16_t*)ws;  ws += (long)H * H * 2;
  bf16_t* WhqT = (bf16_t*)ws;  ws += (long)Q * H * 2;

  hipMemsetAsync(flags, 0, 256 * 64, stream);

  // --- convert inputs to bf16 (weights transposed to N x K) ---
  conv_f32_bf16<<<(int)(MB * D / 8 / 256), 256, 0, stream>>>(x, x_bf, MB * D);
  conv_f32_bf16<<<(int)((long)B * H / 8 / 256), 256, 0, stream>>>(h0, h0bf,
                                                                  (long)B * H);
  transpose_conv<<<dim3(H / 32, D / 32), dim3(32, 8), 0, stream>>>(Wxh, WxhT, D, H);
  transpose_conv<<<dim3(H / 32, H / 32), dim3(32, 8), 0, stream>>>(Whh, WhhT, H, H);
  transpose_conv<<<dim3(Q / 32, H / 32), dim3(32, 8), 0, stream>>>(Whq, WhqT, H, Q);

  // --- Z = x @ W_xh + b_h  (all timesteps), bf16 into Hbuf ---
  gemm_bt_128<1><<<dim3(H / 128, MB / 128), 256, 0, stream>>>(
      x_bf, WxhT, bh, Hbuf, (int)MB, H, D);

  // --- entire recurrence in ONE persistent, fence-free kernel ---
  rnn_persistent4<<<256, 256, 0, stream>>>(h0bf, Hbuf, WhhT, flags);

  // --- out = H @ W_hq + b_q  (fp32 straight to d_out) ---
  gemm_bt_128<0><<<dim3(Q / 128, MB / 128), 256, 0, stream>>>(
      Hbuf, WhqT, bq, out, (int)MB, Q, H);

  // --- final h (fp32) appended after (T*B, Q) block ---
  conv_bf16_f32<<<(int)((long)B * H / 256), 256, 0, stream>>>(
      Hbuf + (long)(T - 1) * B * H, out + MB * Q, (long)B * H);
}